// Round 4
// baseline (4454.438 us; speedup 1.0000x reference)
//
#include <hip/hip_runtime.h>

// Problem constants: B=64, S=256, DIM=512, Q=8, K=1024
#define NROWS   16384
#define DIM     512
#define QQ      8
#define KK      1024
#define QOUT_SZ (NROWS * DIM)
#define IDX_SZ  (NROWS * QQ)

#define MARGIN  0.5f   // >> worst-case bf16x3-vs-fp32 distance error (~0.013)

typedef __attribute__((ext_vector_type(8))) short short8x;   // 8 bf16 = 4 VGPR MFMA frag
typedef __attribute__((ext_vector_type(4))) float f32x4;     // MFMA acc

typedef __attribute__((address_space(3))) uint32_t lds_u32;
typedef __attribute__((address_space(1))) const uint32_t ga_u32;
#define GLOBAL_LOAD_LDS16(g, l) \
    __builtin_amdgcn_global_load_lds((ga_u32*)(g), (lds_u32*)(l), 16, 0, 0)

// ---------------- ws layout (~68 MB) ----------------
#define WS_LOSSP_OFF 0                                   // 512 doubles
#define WS_IDX_OFF   (512 * 8)                           // NROWS int
#define WS_ENORM_OFF (WS_IDX_OFF + NROWS * 4)            // QQ*KK float
#define WS_RNORM_OFF (WS_ENORM_OFF + QQ * KK * 4)        // NROWS float
#define WS_PD1_OFF   (WS_RNORM_OFF + NROWS * 4)          // 4*NROWS float
#define WS_PK1_OFF   (WS_PD1_OFF + 4 * NROWS * 4)        // 4*NROWS int
#define WS_PD2_OFF   (WS_PK1_OFF + 4 * NROWS * 4)        // 4*NROWS float
#define WS_EH_OFF    (WS_PD2_OFF + 4 * NROWS * 4)        // KK*DIM bf16 (current q)
#define WS_EL_OFF    (WS_EH_OFF + KK * DIM * 2)
#define WS_XH_OFF    (WS_EL_OFF + KK * DIM * 2)          // NROWS*DIM bf16
#define WS_XL_OFF    (WS_XH_OFF + (size_t)NROWS * DIM * 2)
#define WS_RES_OFF   (WS_XL_OFF + (size_t)NROWS * DIM * 2)   // NROWS*DIM fp32 (ground truth)

__device__ inline float bf16f(unsigned short h) {
    return __uint_as_float(((unsigned int)h) << 16);
}
// RNE fp32 -> (bf16 hi, bf16 lo) split; hi+lo == f to ~2^-17 rel
__device__ inline void split_bf16(float f, unsigned short& h, unsigned short& l) {
    unsigned int u  = __float_as_uint(f);
    unsigned int hr = (u + 0x7FFFu + ((u >> 16) & 1u)) & 0xFFFF0000u;
    h = (unsigned short)(hr >> 16);
    float fl = f - __uint_as_float(hr);
    unsigned int ul = __float_as_uint(fl);
    l = (unsigned short)((ul + 0x7FFFu + ((ul >> 16) & 1u)) >> 16);
}

// enorm over all QQ*KK embed rows (fp32 — same reduction as passing rounds)
__global__ __launch_bounds__(256) void k_enorm(const float4* __restrict__ e4,
                                               float* __restrict__ enorm) {
    int row  = blockIdx.x * 4 + (threadIdx.x >> 6);
    int lane = threadIdx.x & 63;
    float s = 0.f;
#pragma unroll
    for (int i = 0; i < 2; i++) {
        int c = lane + i * 64;
        float4 v = e4[row * (DIM / 4) + c];
        s += v.x * v.x + v.y * v.y + v.z * v.z + v.w * v.w;
    }
#pragma unroll
    for (int off = 32; off; off >>= 1) s += __shfl_down(s, off, 64);
    if (lane == 0) enorm[row] = s;
}

// res = x, rnorm[row] = sum(x^2). 4 rows/block, wave per row.
__global__ __launch_bounds__(256) void k_prep(const float4* __restrict__ x4,
                                              float4* __restrict__ res4,
                                              float* __restrict__ rnorm) {
    int row  = blockIdx.x * 4 + (threadIdx.x >> 6);
    int lane = threadIdx.x & 63;
    float s = 0.f;
#pragma unroll
    for (int i = 0; i < 2; i++) {
        int c = lane + i * 64;
        float4 v = x4[row * (DIM / 4) + c];
        res4[row * (DIM / 4) + c] = v;
        s += v.x * v.x + v.y * v.y + v.z * v.z + v.w * v.w;
    }
#pragma unroll
    for (int off = 32; off; off >>= 1) s += __shfl_down(s, off, 64);
    if (lane == 0) rnorm[row] = s;
}

// split a fp32 array into bf16 (hi,lo) pair arrays; one float4 per thread
__global__ __launch_bounds__(256) void k_split(const float4* __restrict__ src,
                                               unsigned short* __restrict__ H,
                                               unsigned short* __restrict__ L) {
    int i = blockIdx.x * 256 + threadIdx.x;
    float4 v = src[i];
    unsigned short h0, l0, h1, l1, h2, l2, h3, l3;
    split_bf16(v.x, h0, l0); split_bf16(v.y, h1, l1);
    split_bf16(v.z, h2, l2); split_bf16(v.w, h3, l3);
    *(ushort4*)&H[i * 4] = make_ushort4(h0, h1, h2, h3);
    *(ushort4*)&L[i * 4] = make_ushort4(l0, l1, l2, l3);
}

// ---- MFMA distance GEMM + per-row (d1,k1,d2) partials ----
// grid 512 = 128 mt x 4 nt. Block tile: 128 rows x 256 codes, K=512 in 16 chunks of 32.
// 8 waves: wm = w>>1 (rows wm*32..+31), wn = w&1 (codes wn*128..+127).
// dist = en[k] - 2*(Xh.Eh + Xh.El + Xl.Eh)   (rnorm constant per row -> dropped here)
__global__ __launch_bounds__(512, 4) void k_gemm(
        const unsigned short* __restrict__ Xh, const unsigned short* __restrict__ Xl,
        const unsigned short* __restrict__ Eh, const unsigned short* __restrict__ El,
        const float* __restrict__ enorm_q,
        float* __restrict__ pd1, int* __restrict__ pk1, float* __restrict__ pd2) {
    __shared__ __align__(16) unsigned short sXh[128 * 32], sXl[128 * 32];
    __shared__ __align__(16) unsigned short sEh[256 * 32], sEl[256 * 32];
    __shared__ float sAd1[2][128]; __shared__ int sAk1[2][128]; __shared__ float sAd2[2][128];

    const int tid = threadIdx.x;
    const int l   = tid & 63;
    const int w   = tid >> 6;
    const int wm  = w >> 1;
    const int wn  = w & 1;
    const int mt  = blockIdx.x >> 2;
    const int nt  = blockIdx.x & 3;
    const int l15 = l & 15;
    const int lq4 = l >> 4;          // quad 0..3
    const int lq  = l >> 2;          // 0..15 (staging row-within-wave)
    const int lk  = l & 3;           // 0..3  (staging 16B quarter)

    f32x4 acc[2][8];
#pragma unroll
    for (int rt = 0; rt < 2; rt++)
#pragma unroll
        for (int ct = 0; ct < 8; ct++) acc[rt][ct] = (f32x4){0.f, 0.f, 0.f, 0.f};

    const unsigned short* gXh  = Xh + (size_t)(mt * 128 + w * 16 + lq) * DIM + lk * 8;
    const unsigned short* gXl  = Xl + (size_t)(mt * 128 + w * 16 + lq) * DIM + lk * 8;
    const unsigned short* gEh0 = Eh + (size_t)(nt * 256 + w * 32 + lq) * DIM + lk * 8;
    const unsigned short* gEh1 = Eh + (size_t)(nt * 256 + w * 32 + 16 + lq) * DIM + lk * 8;
    const unsigned short* gEl0 = El + (size_t)(nt * 256 + w * 32 + lq) * DIM + lk * 8;
    const unsigned short* gEl1 = El + (size_t)(nt * 256 + w * 32 + 16 + lq) * DIM + lk * 8;

    for (int c = 0; c < 16; c++) {
        __syncthreads();
        GLOBAL_LOAD_LDS16(gXh  + c * 32, &sXh[w * 512]);
        GLOBAL_LOAD_LDS16(gXl  + c * 32, &sXl[w * 512]);
        GLOBAL_LOAD_LDS16(gEh0 + c * 32, &sEh[(w * 32) * 32]);
        GLOBAL_LOAD_LDS16(gEh1 + c * 32, &sEh[(w * 32 + 16) * 32]);
        GLOBAL_LOAD_LDS16(gEl0 + c * 32, &sEl[(w * 32) * 32]);
        GLOBAL_LOAD_LDS16(gEl1 + c * 32, &sEl[(w * 32 + 16) * 32]);
        __syncthreads();

        // A frag layout: A[m = l&15][k = quad*8 + j]  (m89/m91-verified)
        const int aoff0 = (wm * 32 + 0 + l15) * 32 + lq4 * 8;
        const int aoff1 = (wm * 32 + 16 + l15) * 32 + lq4 * 8;
        short8x ah0 = *(const short8x*)&sXh[aoff0];
        short8x ah1 = *(const short8x*)&sXh[aoff1];
        short8x al0 = *(const short8x*)&sXl[aoff0];
        short8x al1 = *(const short8x*)&sXl[aoff1];

#pragma unroll
        for (int ct = 0; ct < 8; ct++) {
            const int boff = (wn * 128 + ct * 16 + l15) * 32 + lq4 * 8;
            short8x bh = *(const short8x*)&sEh[boff];
            short8x bl = *(const short8x*)&sEl[boff];
            acc[0][ct] = __builtin_amdgcn_mfma_f32_16x16x32_bf16(ah0, bh, acc[0][ct], 0, 0, 0);
            acc[1][ct] = __builtin_amdgcn_mfma_f32_16x16x32_bf16(ah1, bh, acc[1][ct], 0, 0, 0);
            acc[0][ct] = __builtin_amdgcn_mfma_f32_16x16x32_bf16(ah0, bl, acc[0][ct], 0, 0, 0);
            acc[1][ct] = __builtin_amdgcn_mfma_f32_16x16x32_bf16(ah1, bl, acc[1][ct], 0, 0, 0);
            acc[0][ct] = __builtin_amdgcn_mfma_f32_16x16x32_bf16(al0, bh, acc[0][ct], 0, 0, 0);
            acc[1][ct] = __builtin_amdgcn_mfma_f32_16x16x32_bf16(al1, bh, acc[1][ct], 0, 0, 0);
        }
    }

    // epilogue: per-lane (d1,k1,d2) over this wave's 128 codes, per row
    float d1[2][4], d2[2][4]; int k1[2][4];
#pragma unroll
    for (int rt = 0; rt < 2; rt++)
#pragma unroll
        for (int r = 0; r < 4; r++) { d1[rt][r] = 3.4e38f; d2[rt][r] = 3.4e38f; k1[rt][r] = 0; }

#pragma unroll
    for (int ct = 0; ct < 8; ct++) {
        int codeg = nt * 256 + wn * 128 + ct * 16 + l15;   // C/D: col = lane&15
        float en = enorm_q[codeg];
#pragma unroll
        for (int rt = 0; rt < 2; rt++)
#pragma unroll
            for (int r = 0; r < 4; r++) {
                float d = en - 2.0f * acc[rt][ct][r];
                if (d < d1[rt][r] || (d == d1[rt][r] && codeg < k1[rt][r])) {
                    d2[rt][r] = d1[rt][r]; d1[rt][r] = d; k1[rt][r] = codeg;
                } else {
                    d2[rt][r] = fminf(d2[rt][r], d);
                }
            }
    }
    // reduce across the 16 lanes sharing a quad (same C rows): masks 1,2,4,8
#pragma unroll
    for (int m = 1; m < 16; m <<= 1) {
#pragma unroll
        for (int rt = 0; rt < 2; rt++)
#pragma unroll
            for (int r = 0; r < 4; r++) {
                float od1 = __shfl_xor(d1[rt][r], m, 64);
                int   ok1 = __shfl_xor(k1[rt][r], m, 64);
                float od2 = __shfl_xor(d2[rt][r], m, 64);
                bool take = (od1 < d1[rt][r]) || (od1 == d1[rt][r] && ok1 < k1[rt][r]);
                float nd2 = take ? fminf(d1[rt][r], od2) : fminf(od1, d2[rt][r]);
                if (take) { d1[rt][r] = od1; k1[rt][r] = ok1; }
                d2[rt][r] = nd2;
            }
    }
    if (l15 == 0) {
#pragma unroll
        for (int rt = 0; rt < 2; rt++)
#pragma unroll
            for (int r = 0; r < 4; r++) {
                int rloc = wm * 32 + rt * 16 + lq4 * 4 + r;   // C/D: row = quad*4 + reg
                sAd1[wn][rloc] = d1[rt][r]; sAk1[wn][rloc] = k1[rt][r]; sAd2[wn][rloc] = d2[rt][r];
            }
    }
    __syncthreads();
    if (tid < 128) {
        float a1 = sAd1[0][tid], a2 = sAd2[0][tid]; int ak = sAk1[0][tid];
        float b1 = sAd1[1][tid], b2 = sAd2[1][tid]; int bk = sAk1[1][tid];
        bool take = (b1 < a1) || (b1 == a1 && bk < ak);
        int grow = mt * 128 + tid;
        pd1[nt * NROWS + grow] = take ? b1 : a1;
        pk1[nt * NROWS + grow] = take ? bk : ak;
        pd2[nt * NROWS + grow] = take ? fminf(a1, b2) : fminf(b1, a2);
    }
}

// combine 4 nt-partials per row; flagged rows (gap < MARGIN) get exact fp32 rescan
// on the TRUE fp32 residual, with the R1/R2-validated formula (rn + en) - 2*dot
// and sequential d=0..511 accumulation order.
__global__ __launch_bounds__(512) void k_combine_rescan(
        const float* __restrict__ pd1, const int* __restrict__ pk1,
        const float* __restrict__ pd2,
        const float* __restrict__ res, const float* __restrict__ rnorm,
        const float* __restrict__ embed_q, const float* __restrict__ enorm_q,
        int* __restrict__ idx) {
    __shared__ int nflag;
    __shared__ int flagged[128];
    __shared__ float rrow[512];
    __shared__ float sd[512]; __shared__ int sk[512];
    const int tid = threadIdx.x;
    if (tid == 0) nflag = 0;
    __syncthreads();

    if (tid < 128) {
        int row = blockIdx.x * 128 + tid;
        float d1 = pd1[row]; int k1 = pk1[row]; float d2 = pd2[row];
#pragma unroll
        for (int nt = 1; nt < 4; nt++) {
            float b1 = pd1[nt * NROWS + row]; int bk = pk1[nt * NROWS + row];
            float b2 = pd2[nt * NROWS + row];
            bool take = (b1 < d1) || (b1 == d1 && bk < k1);
            float nd2 = take ? fminf(d1, b2) : fminf(b1, d2);
            if (take) { d1 = b1; k1 = bk; }
            d2 = nd2;
        }
        idx[row] = k1;
        if (d2 - d1 < MARGIN) { int p = atomicAdd(&nflag, 1); flagged[p] = row; }
    }
    __syncthreads();
    const int nf = nflag;
    for (int f = 0; f < nf; f++) {
        int row = flagged[f];
        rrow[tid] = res[(size_t)row * DIM + tid];
        __syncthreads();
        float rn = rnorm[row];
        float bd = 3.4e38f; int bk = 0;
#pragma unroll
        for (int cc = 0; cc < 2; cc++) {
            int k = tid + cc * 512;
            const float4* ef = (const float4*)&embed_q[(size_t)k * DIM];
            float dot = 0.f;
            for (int d4 = 0; d4 < 128; d4++) {
                float4 e = ef[d4];
                dot += rrow[d4 * 4 + 0] * e.x; dot += rrow[d4 * 4 + 1] * e.y;
                dot += rrow[d4 * 4 + 2] * e.z; dot += rrow[d4 * 4 + 3] * e.w;
            }
            float dist = (rn + enorm_q[k]) - 2.0f * dot;
            if (dist < bd || (dist == bd && k < bk)) { bd = dist; bk = k; }
        }
        sd[tid] = bd; sk[tid] = bk;
        __syncthreads();
        for (int s = 256; s > 0; s >>= 1) {
            if (tid < s) {
                float o = sd[tid + s]; int ok = sk[tid + s];
                if (o < sd[tid] || (o == sd[tid] && ok < sk[tid])) { sd[tid] = o; sk[tid] = ok; }
            }
            __syncthreads();
        }
        if (tid == 0) idx[row] = sk[0];
        __syncthreads();
    }
}

// residual update on the TRUE fp32 residual (R2 arithmetic), + regenerate split
// pair for next step's GEMM, + loss + rnorm + index output. 32 rows/block.
__global__ __launch_bounds__(512) void k_update(
        float* __restrict__ res,
        unsigned short* __restrict__ Xh, unsigned short* __restrict__ Xl,
        const float* __restrict__ embed_q, const int* __restrict__ idx,
        float* __restrict__ rnorm, double* __restrict__ loss_part,
        float* __restrict__ out_idx, int q) {
    __shared__ float ls_loss[8];
    const int tid = threadIdx.x;
    const int wave = tid >> 6, lid = tid & 63;
    const int row = blockIdx.x * 32 + (tid >> 4);
    const int seg = tid & 15;
    const int k = idx[row];
    const size_t base = (size_t)row * DIM + seg * 32;
    const float* erow = embed_q + (size_t)k * DIM + seg * 32;
    float sl = 0.f, sr = 0.f;
#pragma unroll
    for (int u = 0; u < 8; u++) {
        float4 rv = *(const float4*)&res[base + u * 4];
        float4 ev = *(const float4*)(erow + u * 4);
        // t = q - r; q_st = r + t; new_r = r - q_st  (exact R2 op order)
        float tx = ev.x - rv.x, ty = ev.y - rv.y, tz = ev.z - rv.z, tw = ev.w - rv.w;
        float qx = rv.x + tx, qy = rv.y + ty, qz = rv.z + tz, qw = rv.w + tw;
        float nx = rv.x - qx, ny = rv.y - qy, nz = rv.z - qz, nw = rv.w - qw;
        *(float4*)&res[base + u * 4] = make_float4(nx, ny, nz, nw);
        unsigned short h0, l0, h1, l1, h2, l2, h3, l3;
        split_bf16(nx, h0, l0); split_bf16(ny, h1, l1);
        split_bf16(nz, h2, l2); split_bf16(nw, h3, l3);
        *(ushort4*)&Xh[base + u * 4] = make_ushort4(h0, h1, h2, h3);
        *(ushort4*)&Xl[base + u * 4] = make_ushort4(l0, l1, l2, l3);
        sl += tx * tx + ty * ty + tz * tz + tw * tw;
        sr += nx * nx + ny * ny + nz * nz + nw * nw;
    }
    if (seg == 0) out_idx[(size_t)row * QQ + q] = (float)k;
    // rnorm: reduce over the 16 lanes of this row
    float srr = sr;
#pragma unroll
    for (int m = 1; m < 16; m <<= 1) srr += __shfl_xor(srr, m, 64);
    if (seg == 0) rnorm[row] = srr;
    // loss: wave then block
#pragma unroll
    for (int m = 1; m < 64; m <<= 1) sl += __shfl_xor(sl, m, 64);
    if (lid == 0) ls_loss[wave] = sl;
    __syncthreads();
    if (tid == 0) {
        float s = 0.f;
#pragma unroll
        for (int w = 0; w < 8; w++) s += ls_loss[w];
        double cur = (q == 0) ? 0.0 : loss_part[blockIdx.x];
        loss_part[blockIdx.x] = cur + (double)s;
    }
}

// qout = x - res_final ; block 0 reduces loss partials
__global__ __launch_bounds__(256) void k_final(const float4* __restrict__ x4,
                                               const float4* __restrict__ res4,
                                               float4* __restrict__ out4,
                                               const double* __restrict__ loss_part,
                                               float* __restrict__ out_scalar) {
    int i = blockIdx.x * 256 + threadIdx.x;
    float4 a = x4[i], b = res4[i];
    out4[i] = make_float4(a.x - b.x, a.y - b.y, a.z - b.z, a.w - b.w);
    if (blockIdx.x == 0 && threadIdx.x < 64) {
        double s = 0.0;
#pragma unroll
        for (int j = 0; j < 8; j++) s += loss_part[threadIdx.x + 64 * j];
#pragma unroll
        for (int m = 1; m < 64; m <<= 1) s += __shfl_xor(s, m, 64);
        if (threadIdx.x == 0) out_scalar[0] = (float)(s * 2.0 / (double)QOUT_SZ);
    }
}

extern "C" void kernel_launch(void* const* d_in, const int* in_sizes, int n_in,
                              void* d_out, int out_size, void* d_ws, size_t ws_size,
                              hipStream_t stream) {
    const float* x      = (const float*)d_in[0];   // [NROWS][DIM]
    const float* embeds = (const float*)d_in[1];   // [QQ][KK][DIM]

    char*   ws        = (char*)d_ws;
    double* loss_part = (double*)(ws + WS_LOSSP_OFF);
    int*    idx       = (int*)   (ws + WS_IDX_OFF);
    float*  enorm     = (float*) (ws + WS_ENORM_OFF);
    float*  rnorm     = (float*) (ws + WS_RNORM_OFF);
    float*  pd1       = (float*) (ws + WS_PD1_OFF);
    int*    pk1       = (int*)   (ws + WS_PK1_OFF);
    float*  pd2       = (float*) (ws + WS_PD2_OFF);
    unsigned short* Eh = (unsigned short*)(ws + WS_EH_OFF);
    unsigned short* El = (unsigned short*)(ws + WS_EL_OFF);
    unsigned short* Xh = (unsigned short*)(ws + WS_XH_OFF);
    unsigned short* Xl = (unsigned short*)(ws + WS_XL_OFF);
    float*  res       = (float*) (ws + WS_RES_OFF);

    float* out_q      = (float*)d_out;
    float* out_idx    = out_q + QOUT_SZ;
    float* out_scalar = out_q + QOUT_SZ + IDX_SZ;

    k_enorm<<<(QQ * KK) / 4, 256, 0, stream>>>((const float4*)embeds, enorm);
    k_prep <<<NROWS / 4, 256, 0, stream>>>((const float4*)x, (float4*)res, rnorm);
    k_split<<<QOUT_SZ / 4 / 256, 256, 0, stream>>>((const float4*)x, Xh, Xl);

    for (int q = 0; q < QQ; q++) {
        const float* embed_q = embeds + (size_t)q * KK * DIM;
        const float* enorm_q = enorm + q * KK;
        k_split<<<(KK * DIM) / 4 / 256, 256, 0, stream>>>((const float4*)embed_q, Eh, El);
        k_gemm<<<512, 512, 0, stream>>>(Xh, Xl, Eh, El, enorm_q, pd1, pk1, pd2);
        k_combine_rescan<<<128, 512, 0, stream>>>(pd1, pk1, pd2, res, rnorm,
                                                  embed_q, enorm_q, idx);
        k_update<<<512, 512, 0, stream>>>(res, Xh, Xl, embed_q, idx, rnorm,
                                          loss_part, out_idx, q);
    }

    k_final<<<QOUT_SZ / 4 / 256, 256, 0, stream>>>((const float4*)x, (const float4*)res,
                                                   (float4*)d_out, loss_part, out_scalar);
}

// Round 5
// 1438.075 us; speedup vs baseline: 3.0975x; 3.0975x over previous
//
#include <hip/hip_runtime.h>

// Problem constants: B=64, S=256, DIM=512, Q=8, K=1024
#define NROWS   16384
#define DIM     512
#define QQ      8
#define KK      1024
#define QOUT_SZ (NROWS * DIM)
#define IDX_SZ  (NROWS * QQ)

// worst-case bf16x3-vs-fp32 distance error <= ~6e-3 (typ. 2e-4); 8x headroom
#define MARGIN  0.05f

typedef __attribute__((ext_vector_type(8))) short short8x;   // 8 bf16 = 4 VGPR MFMA frag
typedef __attribute__((ext_vector_type(4))) float f32x4;     // MFMA acc

typedef __attribute__((address_space(3))) uint32_t lds_u32;
typedef __attribute__((address_space(1))) const uint32_t ga_u32;
#define GLOBAL_LOAD_LDS16(g, l) \
    __builtin_amdgcn_global_load_lds((ga_u32*)(g), (lds_u32*)(l), 16, 0, 0)

// ---------------- ws layout (~68 MB) ----------------
#define WS_LOSSP_OFF 0                                   // 512 doubles
#define WS_IDX_OFF   (512 * 8)                           // NROWS int
#define WS_NFLAG_OFF (WS_IDX_OFF + NROWS * 4)            // 1 int (+pad)
#define WS_FLAG_OFF  (WS_NFLAG_OFF + 16)                 // NROWS int
#define WS_ENORM_OFF (WS_FLAG_OFF + NROWS * 4)           // QQ*KK float
#define WS_RNORM_OFF (WS_ENORM_OFF + QQ * KK * 4)        // NROWS float
#define WS_PD1_OFF   (WS_RNORM_OFF + NROWS * 4)          // 4*NROWS float
#define WS_PK1_OFF   (WS_PD1_OFF + 4 * NROWS * 4)        // 4*NROWS int
#define WS_PD2_OFF   (WS_PK1_OFF + 4 * NROWS * 4)        // 4*NROWS float
#define WS_EH_OFF    (WS_PD2_OFF + 4 * NROWS * 4)        // KK*DIM bf16 (current q)
#define WS_EL_OFF    (WS_EH_OFF + KK * DIM * 2)
#define WS_XH_OFF    (WS_EL_OFF + KK * DIM * 2)          // NROWS*DIM bf16
#define WS_XL_OFF    (WS_XH_OFF + (size_t)NROWS * DIM * 2)
#define WS_RES_OFF   (WS_XL_OFF + (size_t)NROWS * DIM * 2)   // NROWS*DIM fp32 (ground truth)

__device__ inline float bf16f(unsigned short h) {
    return __uint_as_float(((unsigned int)h) << 16);
}
// RNE fp32 -> (bf16 hi, bf16 lo) split; hi+lo == f to ~2^-17 rel
__device__ inline void split_bf16(float f, unsigned short& h, unsigned short& l) {
    unsigned int u  = __float_as_uint(f);
    unsigned int hr = (u + 0x7FFFu + ((u >> 16) & 1u)) & 0xFFFF0000u;
    h = (unsigned short)(hr >> 16);
    float fl = f - __uint_as_float(hr);
    unsigned int ul = __float_as_uint(fl);
    l = (unsigned short)((ul + 0x7FFFu + ((ul >> 16) & 1u)) >> 16);
}

// enorm over all QQ*KK embed rows (fp32 — same reduction as passing rounds)
__global__ __launch_bounds__(256) void k_enorm(const float4* __restrict__ e4,
                                               float* __restrict__ enorm) {
    int row  = blockIdx.x * 4 + (threadIdx.x >> 6);
    int lane = threadIdx.x & 63;
    float s = 0.f;
#pragma unroll
    for (int i = 0; i < 2; i++) {
        int c = lane + i * 64;
        float4 v = e4[row * (DIM / 4) + c];
        s += v.x * v.x + v.y * v.y + v.z * v.z + v.w * v.w;
    }
#pragma unroll
    for (int off = 32; off; off >>= 1) s += __shfl_down(s, off, 64);
    if (lane == 0) enorm[row] = s;
}

// res = x, rnorm[row] = sum(x^2). 4 rows/block, wave per row.
__global__ __launch_bounds__(256) void k_prep(const float4* __restrict__ x4,
                                              float4* __restrict__ res4,
                                              float* __restrict__ rnorm) {
    int row  = blockIdx.x * 4 + (threadIdx.x >> 6);
    int lane = threadIdx.x & 63;
    float s = 0.f;
#pragma unroll
    for (int i = 0; i < 2; i++) {
        int c = lane + i * 64;
        float4 v = x4[row * (DIM / 4) + c];
        res4[row * (DIM / 4) + c] = v;
        s += v.x * v.x + v.y * v.y + v.z * v.z + v.w * v.w;
    }
#pragma unroll
    for (int off = 32; off; off >>= 1) s += __shfl_down(s, off, 64);
    if (lane == 0) rnorm[row] = s;
}

// split a fp32 array into bf16 (hi,lo) pair arrays; one float4 per thread
__global__ __launch_bounds__(256) void k_split(const float4* __restrict__ src,
                                               unsigned short* __restrict__ H,
                                               unsigned short* __restrict__ L) {
    int i = blockIdx.x * 256 + threadIdx.x;
    float4 v = src[i];
    unsigned short h0, l0, h1, l1, h2, l2, h3, l3;
    split_bf16(v.x, h0, l0); split_bf16(v.y, h1, l1);
    split_bf16(v.z, h2, l2); split_bf16(v.w, h3, l3);
    *(ushort4*)&H[i * 4] = make_ushort4(h0, h1, h2, h3);
    *(ushort4*)&L[i * 4] = make_ushort4(l0, l1, l2, l3);
}

// ---- MFMA distance GEMM + per-row (d1,k1,d2) partials ----
// grid 512 = 128 mt x 4 nt. Block tile: 128 rows x 256 codes, K=512 in 16 chunks of 32.
// dist = en[k] - 2*(Xh.Eh + Xh.El + Xl.Eh)   (rnorm constant per row -> dropped here)
__global__ __launch_bounds__(512, 4) void k_gemm(
        const unsigned short* __restrict__ Xh, const unsigned short* __restrict__ Xl,
        const unsigned short* __restrict__ Eh, const unsigned short* __restrict__ El,
        const float* __restrict__ enorm_q,
        float* __restrict__ pd1, int* __restrict__ pk1, float* __restrict__ pd2,
        int* __restrict__ nflag) {
    __shared__ __align__(16) unsigned short sXh[128 * 32], sXl[128 * 32];
    __shared__ __align__(16) unsigned short sEh[256 * 32], sEl[256 * 32];
    __shared__ float sAd1[2][128]; __shared__ int sAk1[2][128]; __shared__ float sAd2[2][128];

    const int tid = threadIdx.x;
    if (blockIdx.x == 0 && tid == 0) *nflag = 0;   // reset flag list for this step
    const int l   = tid & 63;
    const int w   = tid >> 6;
    const int wm  = w >> 1;
    const int wn  = w & 1;
    const int mt  = blockIdx.x >> 2;
    const int nt  = blockIdx.x & 3;
    const int l15 = l & 15;
    const int lq4 = l >> 4;          // quad 0..3
    const int lq  = l >> 2;          // 0..15 (staging row-within-wave)
    const int lk  = l & 3;           // 0..3  (staging 16B quarter)

    f32x4 acc[2][8];
#pragma unroll
    for (int rt = 0; rt < 2; rt++)
#pragma unroll
        for (int ct = 0; ct < 8; ct++) acc[rt][ct] = (f32x4){0.f, 0.f, 0.f, 0.f};

    const unsigned short* gXh  = Xh + (size_t)(mt * 128 + w * 16 + lq) * DIM + lk * 8;
    const unsigned short* gXl  = Xl + (size_t)(mt * 128 + w * 16 + lq) * DIM + lk * 8;
    const unsigned short* gEh0 = Eh + (size_t)(nt * 256 + w * 32 + lq) * DIM + lk * 8;
    const unsigned short* gEh1 = Eh + (size_t)(nt * 256 + w * 32 + 16 + lq) * DIM + lk * 8;
    const unsigned short* gEl0 = El + (size_t)(nt * 256 + w * 32 + lq) * DIM + lk * 8;
    const unsigned short* gEl1 = El + (size_t)(nt * 256 + w * 32 + 16 + lq) * DIM + lk * 8;

    for (int c = 0; c < 16; c++) {
        __syncthreads();
        GLOBAL_LOAD_LDS16(gXh  + c * 32, &sXh[w * 512]);
        GLOBAL_LOAD_LDS16(gXl  + c * 32, &sXl[w * 512]);
        GLOBAL_LOAD_LDS16(gEh0 + c * 32, &sEh[(w * 32) * 32]);
        GLOBAL_LOAD_LDS16(gEh1 + c * 32, &sEh[(w * 32 + 16) * 32]);
        GLOBAL_LOAD_LDS16(gEl0 + c * 32, &sEl[(w * 32) * 32]);
        GLOBAL_LOAD_LDS16(gEl1 + c * 32, &sEl[(w * 32 + 16) * 32]);
        __syncthreads();

        // A frag layout: A[m = l&15][k = quad*8 + j]  (m89/m91-verified)
        const int aoff0 = (wm * 32 + 0 + l15) * 32 + lq4 * 8;
        const int aoff1 = (wm * 32 + 16 + l15) * 32 + lq4 * 8;
        short8x ah0 = *(const short8x*)&sXh[aoff0];
        short8x ah1 = *(const short8x*)&sXh[aoff1];
        short8x al0 = *(const short8x*)&sXl[aoff0];
        short8x al1 = *(const short8x*)&sXl[aoff1];

#pragma unroll
        for (int ct = 0; ct < 8; ct++) {
            const int boff = (wn * 128 + ct * 16 + l15) * 32 + lq4 * 8;
            short8x bh = *(const short8x*)&sEh[boff];
            short8x bl = *(const short8x*)&sEl[boff];
            acc[0][ct] = __builtin_amdgcn_mfma_f32_16x16x32_bf16(ah0, bh, acc[0][ct], 0, 0, 0);
            acc[1][ct] = __builtin_amdgcn_mfma_f32_16x16x32_bf16(ah1, bh, acc[1][ct], 0, 0, 0);
            acc[0][ct] = __builtin_amdgcn_mfma_f32_16x16x32_bf16(ah0, bl, acc[0][ct], 0, 0, 0);
            acc[1][ct] = __builtin_amdgcn_mfma_f32_16x16x32_bf16(ah1, bl, acc[1][ct], 0, 0, 0);
            acc[0][ct] = __builtin_amdgcn_mfma_f32_16x16x32_bf16(al0, bh, acc[0][ct], 0, 0, 0);
            acc[1][ct] = __builtin_amdgcn_mfma_f32_16x16x32_bf16(al1, bh, acc[1][ct], 0, 0, 0);
        }
    }

    // epilogue: per-lane (d1,k1,d2) over this wave's 128 codes, per row
    float d1[2][4], d2[2][4]; int k1[2][4];
#pragma unroll
    for (int rt = 0; rt < 2; rt++)
#pragma unroll
        for (int r = 0; r < 4; r++) { d1[rt][r] = 3.4e38f; d2[rt][r] = 3.4e38f; k1[rt][r] = 0; }

#pragma unroll
    for (int ct = 0; ct < 8; ct++) {
        int codeg = nt * 256 + wn * 128 + ct * 16 + l15;   // C/D: col = lane&15
        float en = enorm_q[codeg];
#pragma unroll
        for (int rt = 0; rt < 2; rt++)
#pragma unroll
            for (int r = 0; r < 4; r++) {
                float d = en - 2.0f * acc[rt][ct][r];
                if (d < d1[rt][r] || (d == d1[rt][r] && codeg < k1[rt][r])) {
                    d2[rt][r] = d1[rt][r]; d1[rt][r] = d; k1[rt][r] = codeg;
                } else {
                    d2[rt][r] = fminf(d2[rt][r], d);
                }
            }
    }
    // reduce across the 16 lanes sharing a quad (same C rows): masks 1,2,4,8
#pragma unroll
    for (int m = 1; m < 16; m <<= 1) {
#pragma unroll
        for (int rt = 0; rt < 2; rt++)
#pragma unroll
            for (int r = 0; r < 4; r++) {
                float od1 = __shfl_xor(d1[rt][r], m, 64);
                int   ok1 = __shfl_xor(k1[rt][r], m, 64);
                float od2 = __shfl_xor(d2[rt][r], m, 64);
                bool take = (od1 < d1[rt][r]) || (od1 == d1[rt][r] && ok1 < k1[rt][r]);
                float nd2 = take ? fminf(d1[rt][r], od2) : fminf(od1, d2[rt][r]);
                if (take) { d1[rt][r] = od1; k1[rt][r] = ok1; }
                d2[rt][r] = nd2;
            }
    }
    if (l15 == 0) {
#pragma unroll
        for (int rt = 0; rt < 2; rt++)
#pragma unroll
            for (int r = 0; r < 4; r++) {
                int rloc = wm * 32 + rt * 16 + lq4 * 4 + r;   // C/D: row = quad*4 + reg
                sAd1[wn][rloc] = d1[rt][r]; sAk1[wn][rloc] = k1[rt][r]; sAd2[wn][rloc] = d2[rt][r];
            }
    }
    __syncthreads();
    if (tid < 128) {
        float a1 = sAd1[0][tid], a2 = sAd2[0][tid]; int ak = sAk1[0][tid];
        float b1 = sAd1[1][tid], b2 = sAd2[1][tid]; int bk = sAk1[1][tid];
        bool take = (b1 < a1) || (b1 == a1 && bk < ak);
        int grow = mt * 128 + tid;
        pd1[nt * NROWS + grow] = take ? b1 : a1;
        pk1[nt * NROWS + grow] = take ? bk : ak;
        pd2[nt * NROWS + grow] = take ? fminf(a1, b2) : fminf(b1, a2);
    }
}

// combine 4 nt-partials per row (one thread per row); flag near-ties to a global list
__global__ __launch_bounds__(512) void k_combine(
        const float* __restrict__ pd1, const int* __restrict__ pk1,
        const float* __restrict__ pd2,
        int* __restrict__ idx, int* __restrict__ nflag, int* __restrict__ flag_list) {
    int row = blockIdx.x * 512 + threadIdx.x;
    float d1 = pd1[row]; int k1 = pk1[row]; float d2 = pd2[row];
#pragma unroll
    for (int nt = 1; nt < 4; nt++) {
        float b1 = pd1[nt * NROWS + row]; int bk = pk1[nt * NROWS + row];
        float b2 = pd2[nt * NROWS + row];
        bool take = (b1 < d1) || (b1 == d1 && bk < k1);
        float nd2 = take ? fminf(d1, b2) : fminf(b1, d2);
        if (take) { d1 = b1; k1 = bk; }
        d2 = nd2;
    }
    idx[row] = k1;
    if (d2 - d1 < MARGIN) {
        int p = atomicAdd(nflag, 1);
        flag_list[p] = row;
    }
}

// exact fp32 rescan of flagged rows — one BLOCK per row, grid-stride over the list.
// Reproduces the R1/R2-validated formula (rn + en) - 2*dot with sequential d order.
__global__ __launch_bounds__(256) void k_rescan(
        const int* __restrict__ nflag, const int* __restrict__ flag_list,
        const float* __restrict__ res, const float* __restrict__ rnorm,
        const float* __restrict__ embed_q, const float* __restrict__ enorm_q,
        int* __restrict__ idx) {
    __shared__ __align__(16) float rrow[DIM];
    __shared__ float sd[256]; __shared__ int sk[256];
    const int tid = threadIdx.x;
    const int nf = *nflag;
    for (int f = blockIdx.x; f < nf; f += gridDim.x) {
        int row = flag_list[f];
        __syncthreads();   // protect rrow reuse across iterations
        if (tid < 128) *(float4*)&rrow[tid * 4] = *(const float4*)&res[(size_t)row * DIM + tid * 4];
        __syncthreads();
        float rn = rnorm[row];
        // 4 independent dots per thread for ILP: codes tid, tid+256, tid+512, tid+768
        float dot[4] = {0.f, 0.f, 0.f, 0.f};
        const float4* e0 = (const float4*)&embed_q[(size_t)(tid + 0)   * DIM];
        const float4* e1 = (const float4*)&embed_q[(size_t)(tid + 256) * DIM];
        const float4* e2 = (const float4*)&embed_q[(size_t)(tid + 512) * DIM];
        const float4* e3 = (const float4*)&embed_q[(size_t)(tid + 768) * DIM];
#pragma unroll 4
        for (int d4 = 0; d4 < 128; d4++) {
            float4 r = *(const float4*)&rrow[d4 * 4];
            float4 a = e0[d4], b = e1[d4], c = e2[d4], e = e3[d4];
            dot[0] += r.x * a.x; dot[0] += r.y * a.y; dot[0] += r.z * a.z; dot[0] += r.w * a.w;
            dot[1] += r.x * b.x; dot[1] += r.y * b.y; dot[1] += r.z * b.z; dot[1] += r.w * b.w;
            dot[2] += r.x * c.x; dot[2] += r.y * c.y; dot[2] += r.z * c.z; dot[2] += r.w * c.w;
            dot[3] += r.x * e.x; dot[3] += r.y * e.y; dot[3] += r.z * e.z; dot[3] += r.w * e.w;
        }
        float bd = 3.4e38f; int bk = 0;
#pragma unroll
        for (int cc = 0; cc < 4; cc++) {
            int k = tid + cc * 256;
            float dist = (rn + enorm_q[k]) - 2.0f * dot[cc];
            if (dist < bd || (dist == bd && k < bk)) { bd = dist; bk = k; }
        }
        sd[tid] = bd; sk[tid] = bk;
        __syncthreads();
        for (int s = 128; s > 0; s >>= 1) {
            if (tid < s) {
                float o = sd[tid + s]; int ok = sk[tid + s];
                if (o < sd[tid] || (o == sd[tid] && ok < sk[tid])) { sd[tid] = o; sk[tid] = ok; }
            }
            __syncthreads();
        }
        if (tid == 0) idx[row] = sk[0];
    }
}

// residual update on the TRUE fp32 residual (R2 arithmetic), + regenerate split
// pair for next step's GEMM, + loss + rnorm + index output. 32 rows/block.
__global__ __launch_bounds__(512) void k_update(
        float* __restrict__ res,
        unsigned short* __restrict__ Xh, unsigned short* __restrict__ Xl,
        const float* __restrict__ embed_q, const int* __restrict__ idx,
        float* __restrict__ rnorm, double* __restrict__ loss_part,
        float* __restrict__ out_idx, int q) {
    __shared__ float ls_loss[8];
    const int tid = threadIdx.x;
    const int wave = tid >> 6, lid = tid & 63;
    const int row = blockIdx.x * 32 + (tid >> 4);
    const int seg = tid & 15;
    const int k = idx[row];
    const size_t base = (size_t)row * DIM + seg * 32;
    const float* erow = embed_q + (size_t)k * DIM + seg * 32;
    float sl = 0.f, sr = 0.f;
#pragma unroll
    for (int u = 0; u < 8; u++) {
        float4 rv = *(const float4*)&res[base + u * 4];
        float4 ev = *(const float4*)(erow + u * 4);
        // t = q - r; q_st = r + t; new_r = r - q_st  (exact R2 op order)
        float tx = ev.x - rv.x, ty = ev.y - rv.y, tz = ev.z - rv.z, tw = ev.w - rv.w;
        float qx = rv.x + tx, qy = rv.y + ty, qz = rv.z + tz, qw = rv.w + tw;
        float nx = rv.x - qx, ny = rv.y - qy, nz = rv.z - qz, nw = rv.w - qw;
        *(float4*)&res[base + u * 4] = make_float4(nx, ny, nz, nw);
        unsigned short h0, l0, h1, l1, h2, l2, h3, l3;
        split_bf16(nx, h0, l0); split_bf16(ny, h1, l1);
        split_bf16(nz, h2, l2); split_bf16(nw, h3, l3);
        *(ushort4*)&Xh[base + u * 4] = make_ushort4(h0, h1, h2, h3);
        *(ushort4*)&Xl[base + u * 4] = make_ushort4(l0, l1, l2, l3);
        sl += tx * tx + ty * ty + tz * tz + tw * tw;
        sr += nx * nx + ny * ny + nz * nz + nw * nw;
    }
    if (seg == 0) out_idx[(size_t)row * QQ + q] = (float)k;
    float srr = sr;
#pragma unroll
    for (int m = 1; m < 16; m <<= 1) srr += __shfl_xor(srr, m, 64);
    if (seg == 0) rnorm[row] = srr;
#pragma unroll
    for (int m = 1; m < 64; m <<= 1) sl += __shfl_xor(sl, m, 64);
    if (lid == 0) ls_loss[wave] = sl;
    __syncthreads();
    if (tid == 0) {
        float s = 0.f;
#pragma unroll
        for (int w = 0; w < 8; w++) s += ls_loss[w];
        double cur = (q == 0) ? 0.0 : loss_part[blockIdx.x];
        loss_part[blockIdx.x] = cur + (double)s;
    }
}

// qout = x - res_final ; block 0 reduces loss partials
__global__ __launch_bounds__(256) void k_final(const float4* __restrict__ x4,
                                               const float4* __restrict__ res4,
                                               float4* __restrict__ out4,
                                               const double* __restrict__ loss_part,
                                               float* __restrict__ out_scalar) {
    int i = blockIdx.x * 256 + threadIdx.x;
    float4 a = x4[i], b = res4[i];
    out4[i] = make_float4(a.x - b.x, a.y - b.y, a.z - b.z, a.w - b.w);
    if (blockIdx.x == 0 && threadIdx.x < 64) {
        double s = 0.0;
#pragma unroll
        for (int j = 0; j < 8; j++) s += loss_part[threadIdx.x + 64 * j];
#pragma unroll
        for (int m = 1; m < 64; m <<= 1) s += __shfl_xor(s, m, 64);
        if (threadIdx.x == 0) out_scalar[0] = (float)(s * 2.0 / (double)QOUT_SZ);
    }
}

extern "C" void kernel_launch(void* const* d_in, const int* in_sizes, int n_in,
                              void* d_out, int out_size, void* d_ws, size_t ws_size,
                              hipStream_t stream) {
    const float* x      = (const float*)d_in[0];   // [NROWS][DIM]
    const float* embeds = (const float*)d_in[1];   // [QQ][KK][DIM]

    char*   ws        = (char*)d_ws;
    double* loss_part = (double*)(ws + WS_LOSSP_OFF);
    int*    idx       = (int*)   (ws + WS_IDX_OFF);
    int*    nflag     = (int*)   (ws + WS_NFLAG_OFF);
    int*    flag_list = (int*)   (ws + WS_FLAG_OFF);
    float*  enorm     = (float*) (ws + WS_ENORM_OFF);
    float*  rnorm     = (float*) (ws + WS_RNORM_OFF);
    float*  pd1       = (float*) (ws + WS_PD1_OFF);
    int*    pk1       = (int*)   (ws + WS_PK1_OFF);
    float*  pd2       = (float*) (ws + WS_PD2_OFF);
    unsigned short* Eh = (unsigned short*)(ws + WS_EH_OFF);
    unsigned short* El = (unsigned short*)(ws + WS_EL_OFF);
    unsigned short* Xh = (unsigned short*)(ws + WS_XH_OFF);
    unsigned short* Xl = (unsigned short*)(ws + WS_XL_OFF);
    float*  res       = (float*) (ws + WS_RES_OFF);

    float* out_q      = (float*)d_out;
    float* out_idx    = out_q + QOUT_SZ;
    float* out_scalar = out_q + QOUT_SZ + IDX_SZ;

    k_enorm<<<(QQ * KK) / 4, 256, 0, stream>>>((const float4*)embeds, enorm);
    k_prep <<<NROWS / 4, 256, 0, stream>>>((const float4*)x, (float4*)res, rnorm);
    k_split<<<QOUT_SZ / 4 / 256, 256, 0, stream>>>((const float4*)x, Xh, Xl);

    for (int q = 0; q < QQ; q++) {
        const float* embed_q = embeds + (size_t)q * KK * DIM;
        const float* enorm_q = enorm + q * KK;
        k_split<<<(KK * DIM) / 4 / 256, 256, 0, stream>>>((const float4*)embed_q, Eh, El);
        k_gemm<<<512, 512, 0, stream>>>(Xh, Xl, Eh, El, enorm_q, pd1, pk1, pd2, nflag);
        k_combine<<<NROWS / 512, 512, 0, stream>>>(pd1, pk1, pd2, idx, nflag, flag_list);
        k_rescan<<<256, 256, 0, stream>>>(nflag, flag_list, res, rnorm,
                                          embed_q, enorm_q, idx);
        k_update<<<512, 512, 0, stream>>>(res, Xh, Xl, embed_q, idx, rnorm,
                                          loss_part, out_idx, q);
    }

    k_final<<<QOUT_SZ / 4 / 256, 256, 0, stream>>>((const float4*)x, (const float4*)res,
                                                   (float4*)d_out, loss_part, out_scalar);
}